// Round 5
// baseline (1492.674 us; speedup 1.0000x reference)
//
#include <hip/hip_runtime.h>
#include <stdint.h>

typedef unsigned short u16;
typedef __attribute__((ext_vector_type(4))) unsigned short u16x4;
typedef __attribute__((ext_vector_type(8))) unsigned short u16x8;
typedef __attribute__((ext_vector_type(8))) __bf16 bf16x8;
typedef __attribute__((ext_vector_type(4))) float f32x4;
typedef __attribute__((ext_vector_type(4))) unsigned int u32x4;

#define TOK 12544   // 16*28*28
#define CEMB 1024

// ---------- scalar helpers ----------
__device__ __forceinline__ float bf2f(u16 u) {
  union { unsigned int i; float f; } x; x.i = ((unsigned int)u) << 16; return x.f;
}
__device__ __forceinline__ u16 f2bf(float f) {
  union { float f; unsigned int i; } x; x.f = f;
  unsigned int u = x.i;
  u += 0x7fffu + ((u >> 16) & 1u);   // RNE
  return (u16)(u >> 16);
}
__device__ __forceinline__ float gelu_f(float x) {
  return 0.5f * x * (1.0f + erff(x * 0.7071067811865476f));
}
__device__ __forceinline__ f32x4 mfma_bf16(bf16x8 a, bf16x8 b, f32x4 c) {
  return __builtin_amdgcn_mfma_f32_16x16x32_bf16(a, b, c, 0, 0, 0);
}
// global -> LDS direct 16B. Proper addrspacecast (C-style cast, NO uintptr_t
// truncation — generic LDS pointers carry aperture bits; truncating faults).
__device__ __forceinline__ void glds16(const void* g, void* l) {
  __builtin_amdgcn_global_load_lds(
      (const __attribute__((address_space(1))) void*)g,
      (__attribute__((address_space(3))) void*)l, 16, 0, 0);
}

// ---------- zero fill (replaces hipMemsetAsync: graph-capture-safe by construction) ----------
__global__ __launch_bounds__(256) void zero_k(u32x4* __restrict__ p) {
  u32x4 z = {0u, 0u, 0u, 0u};
  p[threadIdx.x] = z;   // one block: 256*16B = 4096B
}

// ---------- weight conversion ----------
__global__ __launch_bounds__(256) void cast_bf16_k(const float* __restrict__ in,
                                                   u16* __restrict__ out, int n) {
  int i = (blockIdx.x * 256 + threadIdx.x) * 4;
  if (i >= n) return;
  float4 v = *(const float4*)(in + i);
  u16x4 o = { f2bf(v.x), f2bf(v.y), f2bf(v.z), f2bf(v.w) };
  *(u16x4*)(out + i) = o;
}

// conv2_w [O=512][I=512][3][3] -> w2r[o][(dy*3+dx)*512 + c]
__global__ __launch_bounds__(256) void permute_c2_k(const float* __restrict__ in,
                                                    u16* __restrict__ out) {
  int idx = blockIdx.x * 256 + threadIdx.x;  // 512*4608
  int o = idx / 4608;
  int rr = idx - o * 4608;
  int pos = rr >> 9;
  int c = rr & 511;
  out[idx] = f2bf(in[(o * 512 + c) * 9 + pos]);
}

// ---------- LayerNorm family: one wave per row ----------
// MODE 0: ln -> bf16 out.  MODE 1: gelu(ln) -> bf16 out.  MODE 2: resid + ln -> f32 out.
template<int COLS, int MODE>
__global__ __launch_bounds__(256)
void ln_k(const float* __restrict__ in, const float* __restrict__ w,
          const float* __restrict__ b, const float* __restrict__ resid,
          u16* __restrict__ outb, float* __restrict__ outf, float eps) {
  int wave = threadIdx.x >> 6, l = threadIdx.x & 63;
  int row = blockIdx.x * 4 + wave;
  const float* x = in + (size_t)row * COLS;
  constexpr int NC = COLS / 256;  // float4 chunks per lane
  float4 v[NC];
  float s = 0.f, ss = 0.f;
#pragma unroll
  for (int c = 0; c < NC; ++c) {
    v[c] = *(const float4*)(x + (c * 64 + l) * 4);
    s  += v[c].x + v[c].y + v[c].z + v[c].w;
    ss += v[c].x * v[c].x + v[c].y * v[c].y + v[c].z * v[c].z + v[c].w * v[c].w;
  }
#pragma unroll
  for (int off = 32; off; off >>= 1) {
    s  += __shfl_xor(s, off, 64);
    ss += __shfl_xor(ss, off, 64);
  }
  float mean = s * (1.f / COLS);
  float var = ss * (1.f / COLS) - mean * mean;
  float rs = rsqrtf(var + eps);
#pragma unroll
  for (int c = 0; c < NC; ++c) {
    int col = (c * 64 + l) * 4;
    float4 wv = *(const float4*)(w + col);
    float4 bv = *(const float4*)(b + col);
    float o0 = (v[c].x - mean) * rs * wv.x + bv.x;
    float o1 = (v[c].y - mean) * rs * wv.y + bv.y;
    float o2 = (v[c].z - mean) * rs * wv.z + bv.z;
    float o3 = (v[c].w - mean) * rs * wv.w + bv.w;
    if constexpr (MODE == 0) {
      u16x4 o = { f2bf(o0), f2bf(o1), f2bf(o2), f2bf(o3) };
      *(u16x4*)(outb + (size_t)row * COLS + col) = o;
    } else if constexpr (MODE == 1) {
      u16x4 o = { f2bf(gelu_f(o0)), f2bf(gelu_f(o1)), f2bf(gelu_f(o2)), f2bf(gelu_f(o3)) };
      *(u16x4*)(outb + (size_t)row * COLS + col) = o;
    } else {
      float4 rv = *(const float4*)(resid + (size_t)row * COLS + col);
      float4 ov = { rv.x + o0, rv.y + o1, rv.z + o2, rv.w + o3 };
      *(float4*)(outf + (size_t)row * COLS + col) = ov;
    }
  }
}

// ---------- tiled bf16 MFMA GEMM: out[M,N] = A[M,K] @ B[N,K]^T ----------
// 128x128 tile, BK=64, 4 waves, global_load_lds staging (m97 structure).
// EPI: 0=QKV scatter(+bias), 1=bias+resid->f32, 2=bias+gelu->bf16,
//      3=bias+resid->f32+bf16, 4=plain->f32.  GATHER: conv2 3x3 implicit-GEMM A.
template<int EPI, bool GATHER>
__global__ __launch_bounds__(256)
void gemm_k(const u16* __restrict__ A, const u16* __restrict__ B,
            int M, int N, int K,
            const float* __restrict__ bias, const float* __restrict__ resid,
            float* __restrict__ outf, u16* __restrict__ outb,
            u16* __restrict__ qg, u16* __restrict__ kg, u16* __restrict__ vg,
            const u16* __restrict__ zeros) {
  __shared__ u16 As[128 * 64];
  __shared__ u16 Bs[128 * 64];
  const int tid = (int)threadIdx.x;
  const int l = tid & 63;
  const int g = l >> 4, r = l & 15;
  const int w = tid >> 6;
  const int wr = w >> 1, wc = w & 1;
  const int rowBase = (int)blockIdx.y * 128;
  const int colBase = (int)blockIdx.x * 128;
  f32x4 acc[4][4] = {};
  const int nk = K >> 6;
  for (int kt = 0; kt < nk; ++kt) {
    __syncthreads();
#pragma unroll
    for (int i = 0; i < 4; ++i) {
      int idx = i * 256 + tid;
      int trow = idx >> 3, tch = idx & 7;
      const u16* ga;
      if constexpr (!GATHER) {
        ga = A + (size_t)(rowBase + trow) * K + (kt << 6) + (tch << 3);
      } else {
        int pos = kt >> 3;          // (dy,dx) 0..8
        int dy = pos / 3, dx = pos - dy * 3;
        int p = rowBase + trow;
        int bb = p / 784; int rem = p - bb * 784;
        int y = rem / 28; int xx = rem - y * 28;
        int sy = y + dy - 1, sx = xx + dx - 1;
        bool ok = ((unsigned)sy < 28u) && ((unsigned)sx < 28u);
        ga = ok ? (A + (size_t)(bb * 784 + sy * 28 + sx) * 512 + ((kt & 7) << 6) + (tch << 3))
                : zeros;
      }
      glds16(ga, &As[idx * 8]);
      const u16* gb = B + (size_t)(colBase + trow) * K + (kt << 6) + (tch << 3);
      glds16(gb, &Bs[idx * 8]);
    }
    __syncthreads();
    bf16x8 af[4][2], bfr[4][2];
#pragma unroll
    for (int m = 0; m < 4; ++m) {
      af[m][0] = *(const bf16x8*)&As[(wr * 64 + m * 16 + r) * 64 + g * 8];
      af[m][1] = *(const bf16x8*)&As[(wr * 64 + m * 16 + r) * 64 + 32 + g * 8];
    }
#pragma unroll
    for (int n = 0; n < 4; ++n) {
      bfr[n][0] = *(const bf16x8*)&Bs[(wc * 64 + n * 16 + r) * 64 + g * 8];
      bfr[n][1] = *(const bf16x8*)&Bs[(wc * 64 + n * 16 + r) * 64 + 32 + g * 8];
    }
#pragma unroll
    for (int m = 0; m < 4; ++m)
#pragma unroll
      for (int n = 0; n < 4; ++n) {
        acc[m][n] = mfma_bf16(af[m][0], bfr[n][0], acc[m][n]);
        acc[m][n] = mfma_bf16(af[m][1], bfr[n][1], acc[m][n]);
      }
  }
  // epilogue: C/D layout col=lane&15, row=(lane>>4)*4+reg  [verified m89/m91]
#pragma unroll
  for (int m = 0; m < 4; ++m) {
#pragma unroll
    for (int i = 0; i < 4; ++i) {
      int row = rowBase + wr * 64 + m * 16 + g * 4 + i;
#pragma unroll
      for (int n = 0; n < 4; ++n) {
        int col = colBase + wc * 64 + n * 16 + r;
        float v = acc[m][n][i];
        if constexpr (EPI == 0) {
          v += bias[col];
          int bb = row / 784; int rem = row - bb * 784;
          int y = rem / 28; int xx = rem - y * 28;
          int win = bb * 4 + (y / 14) * 2 + (xx / 14);
          int qrow = (y % 14) * 14 + (xx % 14);
          int which = col >> 10; int cid = col & 1023;
          int head = cid >> 6; int d = cid & 63;
          int wh = win * 16 + head;
          u16 bv = f2bf(v);
          if (which == 0)      qg[((size_t)wh * 196 + qrow) * 64 + d] = bv;
          else if (which == 1) kg[((size_t)wh * 196 + qrow) * 64 + d] = bv;
          else                 vg[((size_t)wh * 64 + d) * 224 + qrow] = bv;  // V pre-transposed
        } else if constexpr (EPI == 1) {
          v += bias[col] + resid[(size_t)row * N + col];
          outf[(size_t)row * N + col] = v;
        } else if constexpr (EPI == 2) {
          v = gelu_f(v + bias[col]);
          outb[(size_t)row * N + col] = f2bf(v);
        } else if constexpr (EPI == 3) {
          v += bias[col] + resid[(size_t)row * N + col];   // resid may alias outf (same elem) - safe
          outf[(size_t)row * N + col] = v;
          outb[(size_t)row * N + col] = f2bf(v);
        } else {
          outf[(size_t)row * N + col] = v;
        }
      }
    }
  }
}

// ---------- rel-pos bias tables: relh[wh][q][kh] = q_vec . rel_pos_h[qi-kh+13] ----------
__global__ __launch_bounds__(256)
void rel_k(const u16* __restrict__ qg, const float* __restrict__ rph,
           const float* __restrict__ rpw, float* __restrict__ relh,
           float* __restrict__ relw) {
  int wh = blockIdx.x;
  for (int pair = (int)threadIdx.x; pair < 392; pair += 256) {
    int table = pair >= 196;
    int q = table ? pair - 196 : pair;
    int qi = q / 14, qj = q - qi * 14;
    int qq = table ? qj : qi;
    const u16* qr = qg + ((size_t)wh * 196 + q) * 64;
    float qv[64];
#pragma unroll
    for (int c8 = 0; c8 < 8; ++c8) {
      u16x8 u = *(const u16x8*)(qr + c8 * 8);
#pragma unroll
      for (int j = 0; j < 8; ++j) qv[c8 * 8 + j] = bf2f(u[j]);
    }
    const float* rp = table ? rpw : rph;
    float* out = (table ? relw : relh) + ((size_t)wh * 196 + q) * 14;
    for (int kq = 0; kq < 14; ++kq) {
      const float* rrow = rp + (qq - kq + 13) * 64;
      float sum = 0.f;
#pragma unroll
      for (int c4 = 0; c4 < 16; ++c4) {
        float4 rv = *(const float4*)(rrow + c4 * 4);
        sum += qv[c4 * 4] * rv.x + qv[c4 * 4 + 1] * rv.y +
               qv[c4 * 4 + 2] * rv.z + qv[c4 * 4 + 3] * rv.w;
      }
      out[kq] = sum;
    }
  }
}

// ---------- windowed attention: one block per (window,head), 4 waves ----------
// Swapped QK^T (S^T = K@Q^T) so the key-softmax is lane-local + 2 shuffles.
__global__ __launch_bounds__(256)
void attn_k(const u16* __restrict__ qg, const u16* __restrict__ kg,
            const u16* __restrict__ vg, const float* __restrict__ relh,
            const float* __restrict__ relw, u16* __restrict__ outb) {
  __shared__ float p_lds[4][32][16];
  __shared__ float o_lds[4][64][17];
  const int wh = blockIdx.x;
  const int tid = (int)threadIdx.x;
  const int w = tid >> 6, l = tid & 63;
  const int g = l >> 4, r = l & 15;
  const int win = wh >> 4, head = wh & 15;
  const size_t qbase = (size_t)wh * 196 * 64;
  const size_t vbase = (size_t)wh * 64 * 224;
  for (int qt = w; qt < 13; qt += 4) {
    int q0 = qt * 16 + r;
    int qc = q0 < 196 ? q0 : 195;
    bf16x8 bq0 = *(const bf16x8*)(qg + qbase + (size_t)qc * 64 + g * 8);
    bf16x8 bq1 = *(const bf16x8*)(qg + qbase + (size_t)qc * 64 + 32 + g * 8);
    f32x4 st[13];
#pragma unroll
    for (int kt = 0; kt < 13; ++kt) {
      int k0 = kt * 16 + r;
      int kc = k0 < 196 ? k0 : 195;
      bf16x8 a0 = *(const bf16x8*)(kg + qbase + (size_t)kc * 64 + g * 8);
      bf16x8 a1 = *(const bf16x8*)(kg + qbase + (size_t)kc * 64 + 32 + g * 8);
      f32x4 z = {0.f, 0.f, 0.f, 0.f};
      z = mfma_bf16(a0, bq0, z);
      z = mfma_bf16(a1, bq1, z);
      st[kt] = z;
    }
    const float* rh = relh + ((size_t)wh * 196 + qc) * 14;
    const float* rw = relw + ((size_t)wh * 196 + qc) * 14;
    float mx = -3.0e38f;
#pragma unroll
    for (int kt = 0; kt < 13; ++kt)
#pragma unroll
      for (int i = 0; i < 4; ++i) {
        int key = kt * 16 + g * 4 + i;
        float sv;
        if (key < 196) {
          int kh = key / 14; int kw = key - kh * 14;
          sv = st[kt][i] * 0.125f + rh[kh] + rw[kw];
        } else sv = -1e30f;
        st[kt][i] = sv;
        mx = fmaxf(mx, sv);
      }
    mx = fmaxf(mx, __shfl_xor(mx, 16, 64));
    mx = fmaxf(mx, __shfl_xor(mx, 32, 64));
    float sum = 0.f;
#pragma unroll
    for (int kt = 0; kt < 13; ++kt)
#pragma unroll
      for (int i = 0; i < 4; ++i) {
        float e = __expf(st[kt][i] - mx);
        st[kt][i] = e;
        sum += e;
      }
    sum += __shfl_xor(sum, 16, 64);
    sum += __shfl_xor(sum, 32, 64);
    float inv = 1.f / sum;
    f32x4 oacc[4] = {};
#pragma unroll
    for (int c = 0; c < 7; ++c) {
      // stage P^T rows c*32..c*32+31 (wave-local LDS re-layout C/D -> B frag)
#pragma unroll
      for (int f2 = 0; f2 < 2; ++f2) {
        int fi = c * 2 + f2;
#pragma unroll
        for (int i = 0; i < 4; ++i) {
          float pv = (fi < 13) ? st[fi][i] * inv : 0.f;
          p_lds[w][f2 * 16 + g * 4 + i][r] = pv;
        }
      }
      union { u16 u[8]; bf16x8 b; } pu;
#pragma unroll
      for (int j = 0; j < 8; ++j) pu.u[j] = f2bf(p_lds[w][g * 8 + j][r]);
      bf16x8 bp = pu.b;
#pragma unroll
      for (int dt = 0; dt < 4; ++dt) {
        bf16x8 av = *(const bf16x8*)(vg + vbase + (size_t)(dt * 16 + r) * 224 + c * 32 + g * 8);
        oacc[dt] = mfma_bf16(av, bp, oacc[dt]);   // out^T[d][q]
      }
    }
    // transpose out^T -> token-major bf16 via LDS
#pragma unroll
    for (int dt = 0; dt < 4; ++dt)
#pragma unroll
      for (int i = 0; i < 4; ++i)
        o_lds[w][dt * 16 + g * 4 + i][r] = oacc[dt][i];
    int ql = l >> 2, dseg = l & 3;
    int q = qt * 16 + ql;
    if (q < 196) {
      int qi2 = q / 14, qj2 = q - qi2 * 14;
      int bb = win >> 2; int wy = (win >> 1) & 1; int wx = win & 1;
      int y = wy * 14 + qi2, xx = wx * 14 + qj2;
      size_t tok = (size_t)bb * 784 + y * 28 + xx;
      u16x8 o0, o1;
#pragma unroll
      for (int jj = 0; jj < 8; ++jj) o0[jj] = f2bf(o_lds[w][dseg * 16 + jj][ql]);
#pragma unroll
      for (int jj = 0; jj < 8; ++jj) o1[jj] = f2bf(o_lds[w][dseg * 16 + 8 + jj][ql]);
      *(u16x8*)(outb + tok * 1024 + head * 64 + dseg * 16) = o0;
      *(u16x8*)(outb + tok * 1024 + head * 64 + dseg * 16 + 8) = o1;
    }
  }
}

// ---------- workspace arena (bytes), 226,689,024 total ----------
// weights (live all launch)
#define OFF_QKVW  ((size_t)0)            // 6291456
#define OFF_PROJW ((size_t)6291456)      // 2097152
#define OFF_FC1W  ((size_t)8388608)      // 8388608
#define OFF_FC2W  ((size_t)16777216)     // 8388608
#define OFF_C1W   ((size_t)25165824)     // 1048576
#define OFF_C2W   ((size_t)26214400)     // 4718592
#define OFF_C3W   ((size_t)30932992)     // 1048576
#define OFF_ZEROS ((size_t)31981568)     // 4096
// R1 (103,219,200): {qg,kg,vg,relh,relw} -> h3 (102,760,448) -> c3f (51,380,224)
#define OFF_R1    ((size_t)33554432)
#define OFF_QG    (OFF_R1)
#define OFF_KG    ((size_t)59244544)
#define OFF_VG    ((size_t)84934656)     // [1024][64][224] bf16
#define OFF_RELH  ((size_t)114294784)
#define OFF_RELW  ((size_t)125534208)
// R2 (25,690,112): h1
#define OFF_R2    ((size_t)136773632)
// R3 (25,690,112): attnb -> h2 -> x2b (disjoint lifetimes)
#define OFF_R3    ((size_t)162463744)
// R4 (25,690,112): c1f -> c2f
#define OFF_R4    ((size_t)188153856)
// R5 (12,845,056): r1 -> r2
#define OFF_R5    ((size_t)213843968)
#define WS_NEEDED ((size_t)226689024)
// x1f / x2f live in d_out (f32, 51,380,224 B): proj writes it, LN2 reads it,
// fc2 reads-as-resid + rewrites it (same-element RMW), final LN adds into it.

extern "C" void kernel_launch(void* const* d_in, const int* in_sizes, int n_in,
                              void* d_out, int out_size, void* d_ws, size_t ws_size,
                              hipStream_t stream) {
  const float* x    = (const float*)d_in[0];
  const float* ln1w = (const float*)d_in[1];
  const float* ln1b = (const float*)d_in[2];
  const float* qkvw = (const float*)d_in[3];
  const float* qkvb = (const float*)d_in[4];
  const float* projw= (const float*)d_in[5];
  const float* projb= (const float*)d_in[6];
  const float* rph  = (const float*)d_in[7];
  const float* rpw  = (const float*)d_in[8];
  const float* ln2w = (const float*)d_in[9];
  const float* ln2b = (const float*)d_in[10];
  const float* fc1w = (const float*)d_in[11];
  const float* fc1b = (const float*)d_in[12];
  const float* fc2w = (const float*)d_in[13];
  const float* fc2b = (const float*)d_in[14];
  const float* c1w  = (const float*)d_in[15];
  const float* n1w  = (const float*)d_in[16];
  const float* n1b  = (const float*)d_in[17];
  const float* c2w  = (const float*)d_in[18];
  const float* n2w  = (const float*)d_in[19];
  const float* n2b  = (const float*)d_in[20];
  const float* c3w  = (const float*)d_in[21];
  const float* n3w  = (const float*)d_in[22];
  const float* n3b  = (const float*)d_in[23];

  if (ws_size < WS_NEEDED) return;  // clean wrong-answer instead of a fault

  char* ws = (char*)d_ws;
  u16* qkvw_b = (u16*)(ws + OFF_QKVW);
  u16* projw_b= (u16*)(ws + OFF_PROJW);
  u16* fc1w_b = (u16*)(ws + OFF_FC1W);
  u16* fc2w_b = (u16*)(ws + OFF_FC2W);
  u16* c1w_b  = (u16*)(ws + OFF_C1W);
  u16* c2w_b  = (u16*)(ws + OFF_C2W);
  u16* c3w_b  = (u16*)(ws + OFF_C3W);
  u16* zerosp = (u16*)(ws + OFF_ZEROS);
  u16* qg   = (u16*)(ws + OFF_QG);
  u16* kg   = (u16*)(ws + OFF_KG);
  u16* vg   = (u16*)(ws + OFF_VG);
  float* relh = (float*)(ws + OFF_RELH);
  float* relw = (float*)(ws + OFF_RELW);
  u16* h3   = (u16*)(ws + OFF_R1);
  float* c3f = (float*)(ws + OFF_R1);
  u16* h1   = (u16*)(ws + OFF_R2);
  u16* attnb = (u16*)(ws + OFF_R3);
  u16* h2   = (u16*)(ws + OFF_R3);
  u16* x2b  = (u16*)(ws + OFF_R3);
  float* c1f = (float*)(ws + OFF_R4);
  float* c2f = (float*)(ws + OFF_R4);
  u16* r1   = (u16*)(ws + OFF_R5);
  u16* r2   = (u16*)(ws + OFF_R5);
  float* x1f = (float*)d_out;   // x1 and x2 residuals live in d_out

  zero_k<<<1, 256, 0, stream>>>((u32x4*)zerosp);
  // weight conversions (every launch: ws is re-poisoned)
  cast_bf16_k<<<3145728 / 1024, 256, 0, stream>>>(qkvw, qkvw_b, 3145728);
  cast_bf16_k<<<1048576 / 1024, 256, 0, stream>>>(projw, projw_b, 1048576);
  cast_bf16_k<<<4194304 / 1024, 256, 0, stream>>>(fc1w, fc1w_b, 4194304);
  cast_bf16_k<<<4194304 / 1024, 256, 0, stream>>>(fc2w, fc2w_b, 4194304);
  cast_bf16_k<<<524288 / 1024, 256, 0, stream>>>(c1w, c1w_b, 524288);
  cast_bf16_k<<<524288 / 1024, 256, 0, stream>>>(c3w, c3w_b, 524288);
  permute_c2_k<<<2359296 / 256, 256, 0, stream>>>(c2w, c2w_b);

  // LN1 -> h1 bf16
  ln_k<1024, 0><<<TOK / 4, 256, 0, stream>>>(x, ln1w, ln1b, nullptr, h1, nullptr, 1e-5f);
  // QKV gemm -> scatter q/k/v (V pre-transposed)
  gemm_k<0, false><<<dim3(3072 / 128, TOK / 128), 256, 0, stream>>>(
      h1, qkvw_b, TOK, 3072, 1024, qkvb, nullptr, nullptr, nullptr, qg, kg, vg, zerosp);
  // rel-pos tables
  rel_k<<<1024, 256, 0, stream>>>(qg, rph, rpw, relh, relw);
  // attention -> attnb bf16 [TOK][1024]
  attn_k<<<1024, 256, 0, stream>>>(qg, kg, vg, relh, relw, attnb);
  // proj + resid(x) -> x1f (in d_out)
  gemm_k<1, false><<<dim3(1024 / 128, TOK / 128), 256, 0, stream>>>(
      attnb, projw_b, TOK, 1024, 1024, projb, x, x1f, nullptr, nullptr, nullptr, nullptr, zerosp);
  // LN2 -> h2
  ln_k<1024, 0><<<TOK / 4, 256, 0, stream>>>(x1f, ln2w, ln2b, nullptr, h2, nullptr, 1e-5f);
  // fc1 + gelu -> h3 bf16
  gemm_k<2, false><<<dim3(4096 / 128, TOK / 128), 256, 0, stream>>>(
      h2, fc1w_b, TOK, 4096, 1024, fc1b, nullptr, nullptr, h3, nullptr, nullptr, nullptr, zerosp);
  // fc2 + resid(x1f,in-place d_out) -> x2f (d_out, f32) + x2b (bf16)
  gemm_k<3, false><<<dim3(1024 / 128, TOK / 128), 256, 0, stream>>>(
      h3, fc2w_b, TOK, 1024, 4096, fc2b, x1f, x1f, x2b, nullptr, nullptr, nullptr, zerosp);
  // conv1 (1x1) -> c1f
  gemm_k<4, false><<<dim3(512 / 128, TOK / 128), 256, 0, stream>>>(
      x2b, c1w_b, TOK, 512, 1024, nullptr, nullptr, c1f, nullptr, nullptr, nullptr, nullptr, zerosp);
  // LN-ch + gelu -> r1 bf16
  ln_k<512, 1><<<TOK / 4, 256, 0, stream>>>(c1f, n1w, n1b, nullptr, r1, nullptr, 1e-6f);
  // conv2 (3x3 implicit gemm, K=4608) -> c2f
  gemm_k<4, true><<<dim3(512 / 128, TOK / 128), 256, 0, stream>>>(
      r1, c2w_b, TOK, 512, 4608, nullptr, nullptr, c2f, nullptr, nullptr, nullptr, nullptr, zerosp);
  // LN-ch + gelu -> r2 bf16
  ln_k<512, 1><<<TOK / 4, 256, 0, stream>>>(c2f, n2w, n2b, nullptr, r2, nullptr, 1e-6f);
  // conv3 (1x1) -> c3f
  gemm_k<4, false><<<dim3(1024 / 128, TOK / 128), 256, 0, stream>>>(
      r2, c3w_b, TOK, 1024, 512, nullptr, nullptr, c3f, nullptr, nullptr, nullptr, nullptr, zerosp);
  // final: d_out = x2f(d_out) + LN-ch(c3f; n3w,n3b)
  ln_k<1024, 2><<<TOK / 4, 256, 0, stream>>>(c3f, n3w, n3b, x1f, nullptr, (float*)d_out, 1e-6f);
}

// Round 6
// 1247.581 us; speedup vs baseline: 1.1965x; 1.1965x over previous
//
#include <hip/hip_runtime.h>
#include <stdint.h>

typedef unsigned short u16;
typedef __attribute__((ext_vector_type(4))) unsigned short u16x4;
typedef __attribute__((ext_vector_type(8))) unsigned short u16x8;
typedef __attribute__((ext_vector_type(8))) __bf16 bf16x8;
typedef __attribute__((ext_vector_type(4))) float f32x4;
typedef __attribute__((ext_vector_type(4))) unsigned int u32x4;

#define TOK 12544   // 16*28*28
#define CEMB 1024

// ---------- scalar helpers ----------
__device__ __forceinline__ float bf2f(u16 u) {
  union { unsigned int i; float f; } x; x.i = ((unsigned int)u) << 16; return x.f;
}
__device__ __forceinline__ u16 f2bf(float f) {
  union { float f; unsigned int i; } x; x.f = f;
  unsigned int u = x.i;
  u += 0x7fffu + ((u >> 16) & 1u);   // RNE
  return (u16)(u >> 16);
}
__device__ __forceinline__ float gelu_f(float x) {
  return 0.5f * x * (1.0f + erff(x * 0.7071067811865476f));
}
__device__ __forceinline__ f32x4 mfma_bf16(bf16x8 a, bf16x8 b, f32x4 c) {
  return __builtin_amdgcn_mfma_f32_16x16x32_bf16(a, b, c, 0, 0, 0);
}
// global -> LDS direct 16B (linear LDS dest = wave base + lane*16)
__device__ __forceinline__ void glds16(const void* g, void* l) {
  __builtin_amdgcn_global_load_lds(
      (const __attribute__((address_space(1))) void*)g,
      (__attribute__((address_space(3))) void*)l, 16, 0, 0);
}

// ---------- zero fill ----------
__global__ __launch_bounds__(256) void zero_k(u32x4* __restrict__ p) {
  u32x4 z = {0u, 0u, 0u, 0u};
  p[threadIdx.x] = z;   // one block: 256*16B = 4096B
}

// ---------- weight conversion ----------
__global__ __launch_bounds__(256) void cast_bf16_k(const float* __restrict__ in,
                                                   u16* __restrict__ out, int n) {
  int i = (blockIdx.x * 256 + threadIdx.x) * 4;
  if (i >= n) return;
  float4 v = *(const float4*)(in + i);
  u16x4 o = { f2bf(v.x), f2bf(v.y), f2bf(v.z), f2bf(v.w) };
  *(u16x4*)(out + i) = o;
}

// conv2_w [O=512][I=512][3][3] -> w2r[o][(dy*3+dx)*512 + c]
__global__ __launch_bounds__(256) void permute_c2_k(const float* __restrict__ in,
                                                    u16* __restrict__ out) {
  int idx = blockIdx.x * 256 + threadIdx.x;  // 512*4608
  int o = idx / 4608;
  int rr = idx - o * 4608;
  int pos = rr >> 9;
  int c = rr & 511;
  out[idx] = f2bf(in[(o * 512 + c) * 9 + pos]);
}

// ---------- LayerNorm family: one wave per row ----------
// MODE 0: ln -> bf16 out.  MODE 1: gelu(ln) -> bf16 out.  MODE 2: resid + ln -> f32 out.
template<int COLS, int MODE>
__global__ __launch_bounds__(256)
void ln_k(const float* __restrict__ in, const float* __restrict__ w,
          const float* __restrict__ b, const float* __restrict__ resid,
          u16* __restrict__ outb, float* __restrict__ outf, float eps) {
  int wave = threadIdx.x >> 6, l = threadIdx.x & 63;
  int row = blockIdx.x * 4 + wave;
  const float* x = in + (size_t)row * COLS;
  constexpr int NC = COLS / 256;  // float4 chunks per lane
  float4 v[NC];
  float s = 0.f, ss = 0.f;
#pragma unroll
  for (int c = 0; c < NC; ++c) {
    v[c] = *(const float4*)(x + (c * 64 + l) * 4);
    s  += v[c].x + v[c].y + v[c].z + v[c].w;
    ss += v[c].x * v[c].x + v[c].y * v[c].y + v[c].z * v[c].z + v[c].w * v[c].w;
  }
#pragma unroll
  for (int off = 32; off; off >>= 1) {
    s  += __shfl_xor(s, off, 64);
    ss += __shfl_xor(ss, off, 64);
  }
  float mean = s * (1.f / COLS);
  float var = ss * (1.f / COLS) - mean * mean;
  float rs = rsqrtf(var + eps);
#pragma unroll
  for (int c = 0; c < NC; ++c) {
    int col = (c * 64 + l) * 4;
    float4 wv = *(const float4*)(w + col);
    float4 bv = *(const float4*)(b + col);
    float o0 = (v[c].x - mean) * rs * wv.x + bv.x;
    float o1 = (v[c].y - mean) * rs * wv.y + bv.y;
    float o2 = (v[c].z - mean) * rs * wv.z + bv.z;
    float o3 = (v[c].w - mean) * rs * wv.w + bv.w;
    if constexpr (MODE == 0) {
      u16x4 o = { f2bf(o0), f2bf(o1), f2bf(o2), f2bf(o3) };
      *(u16x4*)(outb + (size_t)row * COLS + col) = o;
    } else if constexpr (MODE == 1) {
      u16x4 o = { f2bf(gelu_f(o0)), f2bf(gelu_f(o1)), f2bf(gelu_f(o2)), f2bf(gelu_f(o3)) };
      *(u16x4*)(outb + (size_t)row * COLS + col) = o;
    } else {
      float4 rv = *(const float4*)(resid + (size_t)row * COLS + col);
      float4 ov = { rv.x + o0, rv.y + o1, rv.z + o2, rv.w + o3 };
      *(float4*)(outf + (size_t)row * COLS + col) = ov;
    }
  }
}

// ---------- tiled bf16 MFMA GEMM: out[M,N] = A[M,K] @ B[N,K]^T ----------
// 128x128 tile, BK=64, 4 waves, global_load_lds staging (m97 structure)
// + T2 chunk-XOR LDS swizzle: data chunk c (16B) of row t lives at LDS chunk
//   c ^ (t&7).  glds dest stays linear; the global SOURCE address is
//   pre-permuted (same 128B row, so coalescing unchanged); ds_read applies
//   the same XOR.  Kills the 128B-stride 16-way bank conflict (3.85e7/dispatch).
// EPI: 0=QKV scatter(+bias), 1=bias+resid->f32, 2=bias+gelu->bf16,
//      3=bias+resid->f32+bf16, 4=plain->f32.  GATHER: conv2 3x3 implicit-GEMM A.
template<int EPI, bool GATHER>
__global__ __launch_bounds__(256)
void gemm_k(const u16* __restrict__ A, const u16* __restrict__ B,
            int M, int N, int K,
            const float* __restrict__ bias, const float* __restrict__ resid,
            float* __restrict__ outf, u16* __restrict__ outb,
            u16* __restrict__ qg, u16* __restrict__ kg, u16* __restrict__ vg,
            const u16* __restrict__ zeros) {
  __shared__ u16 As[128 * 64];
  __shared__ u16 Bs[128 * 64];
  const int tid = (int)threadIdx.x;
  const int l = tid & 63;
  const int g = l >> 4, r = l & 15;
  const int w = tid >> 6;
  const int wr = w >> 1, wc = w & 1;
  const int rowBase = (int)blockIdx.y * 128;
  const int colBase = (int)blockIdx.x * 128;
  f32x4 acc[4][4] = {};
  const int nk = K >> 6;
  for (int kt = 0; kt < nk; ++kt) {
    __syncthreads();
#pragma unroll
    for (int i = 0; i < 4; ++i) {
      int idx = i * 256 + tid;
      int trow = idx >> 3, tch = idx & 7;
      int tchs = tch ^ (trow & 7);        // pre-swizzled source chunk
      const u16* ga;
      if constexpr (!GATHER) {
        ga = A + (size_t)(rowBase + trow) * K + (kt << 6) + (tchs << 3);
      } else {
        int pos = kt >> 3;          // (dy,dx) 0..8
        int dy = pos / 3, dx = pos - dy * 3;
        int p = rowBase + trow;
        int bb = p / 784; int rem = p - bb * 784;
        int y = rem / 28; int xx = rem - y * 28;
        int sy = y + dy - 1, sx = xx + dx - 1;
        bool ok = ((unsigned)sy < 28u) && ((unsigned)sx < 28u);
        ga = ok ? (A + (size_t)(bb * 784 + sy * 28 + sx) * 512 + ((kt & 7) << 6) + (tchs << 3))
                : zeros;
      }
      glds16(ga, &As[idx * 8]);
      const u16* gb = B + (size_t)(colBase + trow) * K + (kt << 6) + (tchs << 3);
      glds16(gb, &Bs[idx * 8]);
    }
    __syncthreads();
    bf16x8 af[4][2], bfr[4][2];
#pragma unroll
    for (int m = 0; m < 4; ++m) {
      int rowA = wr * 64 + m * 16 + r;
      int sA = rowA & 7;
      af[m][0] = *(const bf16x8*)&As[rowA * 64 + ((g ^ sA) << 3)];
      af[m][1] = *(const bf16x8*)&As[rowA * 64 + (((g + 4) ^ sA) << 3)];
    }
#pragma unroll
    for (int n = 0; n < 4; ++n) {
      int rowB = wc * 64 + n * 16 + r;
      int sB = rowB & 7;
      bfr[n][0] = *(const bf16x8*)&Bs[rowB * 64 + ((g ^ sB) << 3)];
      bfr[n][1] = *(const bf16x8*)&Bs[rowB * 64 + (((g + 4) ^ sB) << 3)];
    }
#pragma unroll
    for (int m = 0; m < 4; ++m)
#pragma unroll
      for (int n = 0; n < 4; ++n) {
        acc[m][n] = mfma_bf16(af[m][0], bfr[n][0], acc[m][n]);
        acc[m][n] = mfma_bf16(af[m][1], bfr[n][1], acc[m][n]);
      }
  }
  // epilogue: C/D layout col=lane&15, row=(lane>>4)*4+reg  [verified m89/m91]
#pragma unroll
  for (int m = 0; m < 4; ++m) {
#pragma unroll
    for (int i = 0; i < 4; ++i) {
      int row = rowBase + wr * 64 + m * 16 + g * 4 + i;
#pragma unroll
      for (int n = 0; n < 4; ++n) {
        int col = colBase + wc * 64 + n * 16 + r;
        float v = acc[m][n][i];
        if constexpr (EPI == 0) {
          v += bias[col];
          int bb = row / 784; int rem = row - bb * 784;
          int y = rem / 28; int xx = rem - y * 28;
          int win = bb * 4 + (y / 14) * 2 + (xx / 14);
          int qrow = (y % 14) * 14 + (xx % 14);
          int which = col >> 10; int cid = col & 1023;
          int head = cid >> 6; int d = cid & 63;
          int wh = win * 16 + head;
          u16 bv = f2bf(v);
          if (which == 0)      qg[((size_t)wh * 196 + qrow) * 64 + d] = bv;
          else if (which == 1) kg[((size_t)wh * 196 + qrow) * 64 + d] = bv;
          else                 vg[((size_t)wh * 64 + d) * 224 + qrow] = bv;  // V pre-transposed
        } else if constexpr (EPI == 1) {
          v += bias[col] + resid[(size_t)row * N + col];
          outf[(size_t)row * N + col] = v;
        } else if constexpr (EPI == 2) {
          v = gelu_f(v + bias[col]);
          outb[(size_t)row * N + col] = f2bf(v);
        } else if constexpr (EPI == 3) {
          v += bias[col] + resid[(size_t)row * N + col];   // resid may alias outf (same elem) - safe
          outf[(size_t)row * N + col] = v;
          outb[(size_t)row * N + col] = f2bf(v);
        } else {
          outf[(size_t)row * N + col] = v;
        }
      }
    }
  }
}

// ---------- rel-pos bias tables: relh[wh][q][kh] = q_vec . rel_pos_h[qi-kh+13] ----------
__global__ __launch_bounds__(256)
void rel_k(const u16* __restrict__ qg, const float* __restrict__ rph,
           const float* __restrict__ rpw, float* __restrict__ relh,
           float* __restrict__ relw) {
  int wh = blockIdx.x;
  for (int pair = (int)threadIdx.x; pair < 392; pair += 256) {
    int table = pair >= 196;
    int q = table ? pair - 196 : pair;
    int qi = q / 14, qj = q - qi * 14;
    int qq = table ? qj : qi;
    const u16* qr = qg + ((size_t)wh * 196 + q) * 64;
    float qv[64];
#pragma unroll
    for (int c8 = 0; c8 < 8; ++c8) {
      u16x8 u = *(const u16x8*)(qr + c8 * 8);
#pragma unroll
      for (int j = 0; j < 8; ++j) qv[c8 * 8 + j] = bf2f(u[j]);
    }
    const float* rp = table ? rpw : rph;
    float* out = (table ? relw : relh) + ((size_t)wh * 196 + q) * 14;
    for (int kq = 0; kq < 14; ++kq) {
      const float* rrow = rp + (qq - kq + 13) * 64;
      float sum = 0.f;
#pragma unroll
      for (int c4 = 0; c4 < 16; ++c4) {
        float4 rv = *(const float4*)(rrow + c4 * 4);
        sum += qv[c4 * 4] * rv.x + qv[c4 * 4 + 1] * rv.y +
               qv[c4 * 4 + 2] * rv.z + qv[c4 * 4 + 3] * rv.w;
      }
      out[kq] = sum;
    }
  }
}

// ---------- windowed attention: one block per (window,head), 4 waves ----------
// Swapped QK^T (S^T = K@Q^T) so the key-softmax is lane-local + 2 shuffles.
__global__ __launch_bounds__(256)
void attn_k(const u16* __restrict__ qg, const u16* __restrict__ kg,
            const u16* __restrict__ vg, const float* __restrict__ relh,
            const float* __restrict__ relw, u16* __restrict__ outb) {
  __shared__ float p_lds[4][32][16];
  __shared__ float o_lds[4][64][17];
  const int wh = blockIdx.x;
  const int tid = (int)threadIdx.x;
  const int w = tid >> 6, l = tid & 63;
  const int g = l >> 4, r = l & 15;
  const int win = wh >> 4, head = wh & 15;
  const size_t qbase = (size_t)wh * 196 * 64;
  const size_t vbase = (size_t)wh * 64 * 224;
  for (int qt = w; qt < 13; qt += 4) {
    int q0 = qt * 16 + r;
    int qc = q0 < 196 ? q0 : 195;
    bf16x8 bq0 = *(const bf16x8*)(qg + qbase + (size_t)qc * 64 + g * 8);
    bf16x8 bq1 = *(const bf16x8*)(qg + qbase + (size_t)qc * 64 + 32 + g * 8);
    f32x4 st[13];
#pragma unroll
    for (int kt = 0; kt < 13; ++kt) {
      int k0 = kt * 16 + r;
      int kc = k0 < 196 ? k0 : 195;
      bf16x8 a0 = *(const bf16x8*)(kg + qbase + (size_t)kc * 64 + g * 8);
      bf16x8 a1 = *(const bf16x8*)(kg + qbase + (size_t)kc * 64 + 32 + g * 8);
      f32x4 z = {0.f, 0.f, 0.f, 0.f};
      z = mfma_bf16(a0, bq0, z);
      z = mfma_bf16(a1, bq1, z);
      st[kt] = z;
    }
    const float* rh = relh + ((size_t)wh * 196 + qc) * 14;
    const float* rw = relw + ((size_t)wh * 196 + qc) * 14;
    float mx = -3.0e38f;
#pragma unroll
    for (int kt = 0; kt < 13; ++kt)
#pragma unroll
      for (int i = 0; i < 4; ++i) {
        int key = kt * 16 + g * 4 + i;
        float sv;
        if (key < 196) {
          int kh = key / 14; int kw = key - kh * 14;
          sv = st[kt][i] * 0.125f + rh[kh] + rw[kw];
        } else sv = -1e30f;
        st[kt][i] = sv;
        mx = fmaxf(mx, sv);
      }
    mx = fmaxf(mx, __shfl_xor(mx, 16, 64));
    mx = fmaxf(mx, __shfl_xor(mx, 32, 64));
    float sum = 0.f;
#pragma unroll
    for (int kt = 0; kt < 13; ++kt)
#pragma unroll
      for (int i = 0; i < 4; ++i) {
        float e = __expf(st[kt][i] - mx);
        st[kt][i] = e;
        sum += e;
      }
    sum += __shfl_xor(sum, 16, 64);
    sum += __shfl_xor(sum, 32, 64);
    float inv = 1.f / sum;
    f32x4 oacc[4] = {};
#pragma unroll
    for (int c = 0; c < 7; ++c) {
      // stage P^T rows c*32..c*32+31 (wave-local LDS re-layout C/D -> B frag)
#pragma unroll
      for (int f2 = 0; f2 < 2; ++f2) {
        int fi = c * 2 + f2;
#pragma unroll
        for (int i = 0; i < 4; ++i) {
          float pv = (fi < 13) ? st[fi][i] * inv : 0.f;
          p_lds[w][f2 * 16 + g * 4 + i][r] = pv;
        }
      }
      union { u16 u[8]; bf16x8 b; } pu;
#pragma unroll
      for (int j = 0; j < 8; ++j) pu.u[j] = f2bf(p_lds[w][g * 8 + j][r]);
      bf16x8 bp = pu.b;
#pragma unroll
      for (int dt = 0; dt < 4; ++dt) {
        bf16x8 av = *(const bf16x8*)(vg + vbase + (size_t)(dt * 16 + r) * 224 + c * 32 + g * 8);
        oacc[dt] = mfma_bf16(av, bp, oacc[dt]);   // out^T[d][q]
      }
    }
    // transpose out^T -> token-major bf16 via LDS
#pragma unroll
    for (int dt = 0; dt < 4; ++dt)
#pragma unroll
      for (int i = 0; i < 4; ++i)
        o_lds[w][dt * 16 + g * 4 + i][r] = oacc[dt][i];
    int ql = l >> 2, dseg = l & 3;
    int q = qt * 16 + ql;
    if (q < 196) {
      int qi2 = q / 14, qj2 = q - qi2 * 14;
      int bb = win >> 2; int wy = (win >> 1) & 1; int wx = win & 1;
      int y = wy * 14 + qi2, xx = wx * 14 + qj2;
      size_t tok = (size_t)bb * 784 + y * 28 + xx;
      u16x8 o0, o1;
#pragma unroll
      for (int jj = 0; jj < 8; ++jj) o0[jj] = f2bf(o_lds[w][dseg * 16 + jj][ql]);
#pragma unroll
      for (int jj = 0; jj < 8; ++jj) o1[jj] = f2bf(o_lds[w][dseg * 16 + 8 + jj][ql]);
      *(u16x8*)(outb + tok * 1024 + head * 64 + dseg * 16) = o0;
      *(u16x8*)(outb + tok * 1024 + head * 64 + dseg * 16 + 8) = o1;
    }
  }
}

// ---------- workspace arena (bytes), 226,689,024 total ----------
#define OFF_QKVW  ((size_t)0)            // 6291456
#define OFF_PROJW ((size_t)6291456)      // 2097152
#define OFF_FC1W  ((size_t)8388608)      // 8388608
#define OFF_FC2W  ((size_t)16777216)     // 8388608
#define OFF_C1W   ((size_t)25165824)     // 1048576
#define OFF_C2W   ((size_t)26214400)     // 4718592
#define OFF_C3W   ((size_t)30932992)     // 1048576
#define OFF_ZEROS ((size_t)31981568)     // 4096
// R1 (103,219,200): {qg,kg,vg,relh,relw} -> h3 (102,760,448) -> c3f (51,380,224)
#define OFF_R1    ((size_t)33554432)
#define OFF_QG    (OFF_R1)
#define OFF_KG    ((size_t)59244544)
#define OFF_VG    ((size_t)84934656)     // [1024][64][224] bf16
#define OFF_RELH  ((size_t)114294784)
#define OFF_RELW  ((size_t)125534208)
// R2 (25,690,112): h1
#define OFF_R2    ((size_t)136773632)
// R3 (25,690,112): attnb -> h2 -> x2b (disjoint lifetimes)
#define OFF_R3    ((size_t)162463744)
// R4 (25,690,112): c1f -> c2f
#define OFF_R4    ((size_t)188153856)
// R5 (12,845,056): r1 -> r2
#define OFF_R5    ((size_t)213843968)
#define WS_NEEDED ((size_t)226689024)
// x1f / x2f live in d_out (f32): proj writes it, LN2 reads it,
// fc2 reads-as-resid + rewrites it (same-element RMW), final LN adds into it.

extern "C" void kernel_launch(void* const* d_in, const int* in_sizes, int n_in,
                              void* d_out, int out_size, void* d_ws, size_t ws_size,
                              hipStream_t stream) {
  const float* x    = (const float*)d_in[0];
  const float* ln1w = (const float*)d_in[1];
  const float* ln1b = (const float*)d_in[2];
  const float* qkvw = (const float*)d_in[3];
  const float* qkvb = (const float*)d_in[4];
  const float* projw= (const float*)d_in[5];
  const float* projb= (const float*)d_in[6];
  const float* rph  = (const float*)d_in[7];
  const float* rpw  = (const float*)d_in[8];
  const float* ln2w = (const float*)d_in[9];
  const float* ln2b = (const float*)d_in[10];
  const float* fc1w = (const float*)d_in[11];
  const float* fc1b = (const float*)d_in[12];
  const float* fc2w = (const float*)d_in[13];
  const float* fc2b = (const float*)d_in[14];
  const float* c1w  = (const float*)d_in[15];
  const float* n1w  = (const float*)d_in[16];
  const float* n1b  = (const float*)d_in[17];
  const float* c2w  = (const float*)d_in[18];
  const float* n2w  = (const float*)d_in[19];
  const float* n2b  = (const float*)d_in[20];
  const float* c3w  = (const float*)d_in[21];
  const float* n3w  = (const float*)d_in[22];
  const float* n3b  = (const float*)d_in[23];

  if (ws_size < WS_NEEDED) return;  // clean wrong-answer instead of a fault

  char* ws = (char*)d_ws;
  u16* qkvw_b = (u16*)(ws + OFF_QKVW);
  u16* projw_b= (u16*)(ws + OFF_PROJW);
  u16* fc1w_b = (u16*)(ws + OFF_FC1W);
  u16* fc2w_b = (u16*)(ws + OFF_FC2W);
  u16* c1w_b  = (u16*)(ws + OFF_C1W);
  u16* c2w_b  = (u16*)(ws + OFF_C2W);
  u16* c3w_b  = (u16*)(ws + OFF_C3W);
  u16* zerosp = (u16*)(ws + OFF_ZEROS);
  u16* qg   = (u16*)(ws + OFF_QG);
  u16* kg   = (u16*)(ws + OFF_KG);
  u16* vg   = (u16*)(ws + OFF_VG);
  float* relh = (float*)(ws + OFF_RELH);
  float* relw = (float*)(ws + OFF_RELW);
  u16* h3   = (u16*)(ws + OFF_R1);
  float* c3f = (float*)(ws + OFF_R1);
  u16* h1   = (u16*)(ws + OFF_R2);
  u16* attnb = (u16*)(ws + OFF_R3);
  u16* h2   = (u16*)(ws + OFF_R3);
  u16* x2b  = (u16*)(ws + OFF_R3);
  float* c1f = (float*)(ws + OFF_R4);
  float* c2f = (float*)(ws + OFF_R4);
  u16* r1   = (u16*)(ws + OFF_R5);
  u16* r2   = (u16*)(ws + OFF_R5);
  float* x1f = (float*)d_out;   // x1 and x2 residuals live in d_out

  zero_k<<<1, 256, 0, stream>>>((u32x4*)zerosp);
  // weight conversions (every launch: ws is re-poisoned)
  cast_bf16_k<<<3145728 / 1024, 256, 0, stream>>>(qkvw, qkvw_b, 3145728);
  cast_bf16_k<<<1048576 / 1024, 256, 0, stream>>>(projw, projw_b, 1048576);
  cast_bf16_k<<<4194304 / 1024, 256, 0, stream>>>(fc1w, fc1w_b, 4194304);
  cast_bf16_k<<<4194304 / 1024, 256, 0, stream>>>(fc2w, fc2w_b, 4194304);
  cast_bf16_k<<<524288 / 1024, 256, 0, stream>>>(c1w, c1w_b, 524288);
  cast_bf16_k<<<524288 / 1024, 256, 0, stream>>>(c3w, c3w_b, 524288);
  permute_c2_k<<<2359296 / 256, 256, 0, stream>>>(c2w, c2w_b);

  // LN1 -> h1 bf16
  ln_k<1024, 0><<<TOK / 4, 256, 0, stream>>>(x, ln1w, ln1b, nullptr, h1, nullptr, 1e-5f);
  // QKV gemm -> scatter q/k/v (V pre-transposed)
  gemm_k<0, false><<<dim3(3072 / 128, TOK / 128), 256, 0, stream>>>(
      h1, qkvw_b, TOK, 3072, 1024, qkvb, nullptr, nullptr, nullptr, qg, kg, vg, zerosp);
  // rel-pos tables
  rel_k<<<1024, 256, 0, stream>>>(qg, rph, rpw, relh, relw);
  // attention -> attnb bf16 [TOK][1024]
  attn_k<<<1024, 256, 0, stream>>>(qg, kg, vg, relh, relw, attnb);
  // proj + resid(x) -> x1f (in d_out)
  gemm_k<1, false><<<dim3(1024 / 128, TOK / 128), 256, 0, stream>>>(
      attnb, projw_b, TOK, 1024, 1024, projb, x, x1f, nullptr, nullptr, nullptr, nullptr, zerosp);
  // LN2 -> h2
  ln_k<1024, 0><<<TOK / 4, 256, 0, stream>>>(x1f, ln2w, ln2b, nullptr, h2, nullptr, 1e-5f);
  // fc1 + gelu -> h3 bf16
  gemm_k<2, false><<<dim3(4096 / 128, TOK / 128), 256, 0, stream>>>(
      h2, fc1w_b, TOK, 4096, 1024, fc1b, nullptr, nullptr, h3, nullptr, nullptr, nullptr, zerosp);
  // fc2 + resid(x1f,in-place d_out) -> x2f (d_out, f32) + x2b (bf16)
  gemm_k<3, false><<<dim3(1024 / 128, TOK / 128), 256, 0, stream>>>(
      h3, fc2w_b, TOK, 1024, 4096, fc2b, x1f, x1f, x2b, nullptr, nullptr, nullptr, zerosp);
  // conv1 (1x1) -> c1f
  gemm_k<4, false><<<dim3(512 / 128, TOK / 128), 256, 0, stream>>>(
      x2b, c1w_b, TOK, 512, 1024, nullptr, nullptr, c1f, nullptr, nullptr, nullptr, nullptr, zerosp);
  // LN-ch + gelu -> r1 bf16
  ln_k<512, 1><<<TOK / 4, 256, 0, stream>>>(c1f, n1w, n1b, nullptr, r1, nullptr, 1e-6f);
  // conv2 (3x3 implicit gemm, K=4608) -> c2f
  gemm_k<4, true><<<dim3(512 / 128, TOK / 128), 256, 0, stream>>>(
      r1, c2w_b, TOK, 512, 4608, nullptr, nullptr, c2f, nullptr, nullptr, nullptr, nullptr, zerosp);
  // LN-ch + gelu -> r2 bf16
  ln_k<512, 1><<<TOK / 4, 256, 0, stream>>>(c2f, n2w, n2b, nullptr, r2, nullptr, 1e-6f);
  // conv3 (1x1) -> c3f
  gemm_k<4, false><<<dim3(1024 / 128, TOK / 128), 256, 0, stream>>>(
      r2, c3w_b, TOK, 1024, 512, nullptr, nullptr, c3f, nullptr, nullptr, nullptr, nullptr, zerosp);
  // final: d_out = x2f(d_out) + LN-ch(c3f; n3w,n3b)
  ln_k<1024, 2><<<TOK / 4, 256, 0, stream>>>(c3f, n3w, n3b, x1f, nullptr, (float*)d_out, 1e-6f);
}

// Round 7
// 1207.844 us; speedup vs baseline: 1.2358x; 1.0329x over previous
//
#include <hip/hip_runtime.h>
#include <stdint.h>

typedef unsigned short u16;
typedef __attribute__((ext_vector_type(4))) unsigned short u16x4;
typedef __attribute__((ext_vector_type(8))) unsigned short u16x8;
typedef __attribute__((ext_vector_type(8))) __bf16 bf16x8;
typedef __attribute__((ext_vector_type(4))) float f32x4;
typedef __attribute__((ext_vector_type(4))) unsigned int u32x4;

#define TOK 12544   // 16*28*28
#define CEMB 1024

// ---------- scalar helpers ----------
__device__ __forceinline__ float bf2f(u16 u) {
  union { unsigned int i; float f; } x; x.i = ((unsigned int)u) << 16; return x.f;
}
__device__ __forceinline__ u16 f2bf(float f) {
  union { float f; unsigned int i; } x; x.f = f;
  unsigned int u = x.i;
  u += 0x7fffu + ((u >> 16) & 1u);   // RNE
  return (u16)(u >> 16);
}
__device__ __forceinline__ float gelu_f(float x) {
  return 0.5f * x * (1.0f + erff(x * 0.7071067811865476f));
}
__device__ __forceinline__ f32x4 mfma_bf16(bf16x8 a, bf16x8 b, f32x4 c) {
  return __builtin_amdgcn_mfma_f32_16x16x32_bf16(a, b, c, 0, 0, 0);
}
// global -> LDS direct 16B (linear LDS dest = wave base + lane*16)
__device__ __forceinline__ void glds16(const void* g, void* l) {
  __builtin_amdgcn_global_load_lds(
      (const __attribute__((address_space(1))) void*)g,
      (__attribute__((address_space(3))) void*)l, 16, 0, 0);
}

// ---------- zero fill ----------
__global__ __launch_bounds__(256) void zero_k(u32x4* __restrict__ p) {
  u32x4 z = {0u, 0u, 0u, 0u};
  p[threadIdx.x] = z;   // one block: 256*16B = 4096B
}

// ---------- weight conversion ----------
__global__ __launch_bounds__(256) void cast_bf16_k(const float* __restrict__ in,
                                                   u16* __restrict__ out, int n) {
  int i = (blockIdx.x * 256 + threadIdx.x) * 4;
  if (i >= n) return;
  float4 v = *(const float4*)(in + i);
  u16x4 o = { f2bf(v.x), f2bf(v.y), f2bf(v.z), f2bf(v.w) };
  *(u16x4*)(out + i) = o;
}

// conv2_w [O=512][I=512][3][3] -> w2r[o][(dy*3+dx)*512 + c]
__global__ __launch_bounds__(256) void permute_c2_k(const float* __restrict__ in,
                                                    u16* __restrict__ out) {
  int idx = blockIdx.x * 256 + threadIdx.x;  // 512*4608
  int o = idx / 4608;
  int rr = idx - o * 4608;
  int pos = rr >> 9;
  int c = rr & 511;
  out[idx] = f2bf(in[(o * 512 + c) * 9 + pos]);
}

// ---------- LayerNorm family: one wave per row ----------
// MODE 0: ln -> bf16 out.  MODE 1: gelu(ln) -> bf16 out.  MODE 2: resid + ln -> f32 out.
template<int COLS, int MODE>
__global__ __launch_bounds__(256)
void ln_k(const float* __restrict__ in, const float* __restrict__ w,
          const float* __restrict__ b, const float* __restrict__ resid,
          u16* __restrict__ outb, float* __restrict__ outf, float eps) {
  int wave = threadIdx.x >> 6, l = threadIdx.x & 63;
  int row = blockIdx.x * 4 + wave;
  const float* x = in + (size_t)row * COLS;
  constexpr int NC = COLS / 256;  // float4 chunks per lane
  float4 v[NC];
  float s = 0.f, ss = 0.f;
#pragma unroll
  for (int c = 0; c < NC; ++c) {
    v[c] = *(const float4*)(x + (c * 64 + l) * 4);
    s  += v[c].x + v[c].y + v[c].z + v[c].w;
    ss += v[c].x * v[c].x + v[c].y * v[c].y + v[c].z * v[c].z + v[c].w * v[c].w;
  }
#pragma unroll
  for (int off = 32; off; off >>= 1) {
    s  += __shfl_xor(s, off, 64);
    ss += __shfl_xor(ss, off, 64);
  }
  float mean = s * (1.f / COLS);
  float var = ss * (1.f / COLS) - mean * mean;
  float rs = rsqrtf(var + eps);
#pragma unroll
  for (int c = 0; c < NC; ++c) {
    int col = (c * 64 + l) * 4;
    float4 wv = *(const float4*)(w + col);
    float4 bv = *(const float4*)(b + col);
    float o0 = (v[c].x - mean) * rs * wv.x + bv.x;
    float o1 = (v[c].y - mean) * rs * wv.y + bv.y;
    float o2 = (v[c].z - mean) * rs * wv.z + bv.z;
    float o3 = (v[c].w - mean) * rs * wv.w + bv.w;
    if constexpr (MODE == 0) {
      u16x4 o = { f2bf(o0), f2bf(o1), f2bf(o2), f2bf(o3) };
      *(u16x4*)(outb + (size_t)row * COLS + col) = o;
    } else if constexpr (MODE == 1) {
      u16x4 o = { f2bf(gelu_f(o0)), f2bf(gelu_f(o1)), f2bf(gelu_f(o2)), f2bf(gelu_f(o3)) };
      *(u16x4*)(outb + (size_t)row * COLS + col) = o;
    } else {
      float4 rv = *(const float4*)(resid + (size_t)row * COLS + col);
      float4 ov = { rv.x + o0, rv.y + o1, rv.z + o2, rv.w + o3 };
      *(float4*)(outf + (size_t)row * COLS + col) = ov;
    }
  }
}

// ---------- tiled bf16 MFMA GEMM: out[M,N] = A[M,K] @ B[N,K]^T ----------
// 128x128 tile, BK=64, 4 waves, global_load_lds staging (m97 structure)
// + T2 chunk-XOR LDS swizzle (round-5: conflicts 3.85e7 -> 0)
// + T1 bijective XCD swizzle: the gx col-blocks of one row-band land on one
//   XCD so the A-panel is fetched into one L2, not eight (fc2 FETCH 434MB->~).
// EPI: 0=QKV scatter(+bias), 1=bias+resid->f32, 2=bias+gelu->bf16,
//      3=bias+resid->f32+bf16, 4=plain->f32.  GATHER: conv2 3x3 implicit-GEMM A.
template<int EPI, bool GATHER>
__global__ __launch_bounds__(256)
void gemm_k(const u16* __restrict__ A, const u16* __restrict__ B,
            int M, int N, int K,
            const float* __restrict__ bias, const float* __restrict__ resid,
            float* __restrict__ outf, u16* __restrict__ outb,
            u16* __restrict__ qg, u16* __restrict__ kg, u16* __restrict__ vg,
            const u16* __restrict__ zeros) {
  __shared__ u16 As[128 * 64];
  __shared__ u16 Bs[128 * 64];
  const int tid = (int)threadIdx.x;
  const int l = tid & 63;
  const int g = l >> 4, r = l & 15;
  const int w = tid >> 6;
  const int wr = w >> 1, wc = w & 1;
  // T1 XCD swizzle (all grids have nwg % 8 == 0)
  const int gx = (int)gridDim.x;
  const int bid = (int)blockIdx.y * gx + (int)blockIdx.x;
  const int cpx = (gx * (int)gridDim.y) >> 3;
  const int swz = (bid & 7) * cpx + (bid >> 3);
  const int rowBase = (swz / gx) * 128;
  const int colBase = (swz % gx) * 128;
  f32x4 acc[4][4] = {};
  const int nk = K >> 6;
  for (int kt = 0; kt < nk; ++kt) {
    __syncthreads();
#pragma unroll
    for (int i = 0; i < 4; ++i) {
      int idx = i * 256 + tid;
      int trow = idx >> 3, tch = idx & 7;
      int tchs = tch ^ (trow & 7);        // pre-swizzled source chunk
      const u16* ga;
      if constexpr (!GATHER) {
        ga = A + (size_t)(rowBase + trow) * K + (kt << 6) + (tchs << 3);
      } else {
        int pos = kt >> 3;          // (dy,dx) 0..8
        int dy = pos / 3, dx = pos - dy * 3;
        int p = rowBase + trow;
        int bb = p / 784; int rem = p - bb * 784;
        int y = rem / 28; int xx = rem - y * 28;
        int sy = y + dy - 1, sx = xx + dx - 1;
        bool ok = ((unsigned)sy < 28u) && ((unsigned)sx < 28u);
        ga = ok ? (A + (size_t)(bb * 784 + sy * 28 + sx) * 512 + ((kt & 7) << 6) + (tchs << 3))
                : zeros;
      }
      glds16(ga, &As[idx * 8]);
      const u16* gb = B + (size_t)(colBase + trow) * K + (kt << 6) + (tchs << 3);
      glds16(gb, &Bs[idx * 8]);
    }
    __syncthreads();
    bf16x8 af[4][2], bfr[4][2];
#pragma unroll
    for (int m = 0; m < 4; ++m) {
      int rowA = wr * 64 + m * 16 + r;
      int sA = rowA & 7;
      af[m][0] = *(const bf16x8*)&As[rowA * 64 + ((g ^ sA) << 3)];
      af[m][1] = *(const bf16x8*)&As[rowA * 64 + (((g + 4) ^ sA) << 3)];
    }
#pragma unroll
    for (int n = 0; n < 4; ++n) {
      int rowB = wc * 64 + n * 16 + r;
      int sB = rowB & 7;
      bfr[n][0] = *(const bf16x8*)&Bs[rowB * 64 + ((g ^ sB) << 3)];
      bfr[n][1] = *(const bf16x8*)&Bs[rowB * 64 + (((g + 4) ^ sB) << 3)];
    }
#pragma unroll
    for (int m = 0; m < 4; ++m)
#pragma unroll
      for (int n = 0; n < 4; ++n) {
        acc[m][n] = mfma_bf16(af[m][0], bfr[n][0], acc[m][n]);
        acc[m][n] = mfma_bf16(af[m][1], bfr[n][1], acc[m][n]);
      }
  }
  // epilogue: C/D layout col=lane&15, row=(lane>>4)*4+reg  [verified m89/m91]
#pragma unroll
  for (int m = 0; m < 4; ++m) {
#pragma unroll
    for (int i = 0; i < 4; ++i) {
      int row = rowBase + wr * 64 + m * 16 + g * 4 + i;
#pragma unroll
      for (int n = 0; n < 4; ++n) {
        int col = colBase + wc * 64 + n * 16 + r;
        float v = acc[m][n][i];
        if constexpr (EPI == 0) {
          v += bias[col];
          int bb = row / 784; int rem = row - bb * 784;
          int y = rem / 28; int xx = rem - y * 28;
          int win = bb * 4 + (y / 14) * 2 + (xx / 14);
          int qrow = (y % 14) * 14 + (xx % 14);
          int which = col >> 10; int cid = col & 1023;
          int head = cid >> 6; int d = cid & 63;
          int wh = win * 16 + head;
          u16 bv = f2bf(v);
          if (which == 0)      qg[((size_t)wh * 196 + qrow) * 64 + d] = bv;
          else if (which == 1) kg[((size_t)wh * 196 + qrow) * 64 + d] = bv;
          else                 vg[((size_t)wh * 64 + d) * 224 + qrow] = bv;  // V pre-transposed
        } else if constexpr (EPI == 1) {
          v += bias[col] + resid[(size_t)row * N + col];
          outf[(size_t)row * N + col] = v;
        } else if constexpr (EPI == 2) {
          v = gelu_f(v + bias[col]);
          outb[(size_t)row * N + col] = f2bf(v);
        } else if constexpr (EPI == 3) {
          v += bias[col] + resid[(size_t)row * N + col];   // resid may alias outf (same elem) - safe
          outf[(size_t)row * N + col] = v;
          outb[(size_t)row * N + col] = f2bf(v);
        } else {
          outf[(size_t)row * N + col] = v;
        }
      }
    }
  }
}

// ---------- rel-pos bias tables: relh[wh][q][kh] = q_vec . rel_pos_h[qi-kh+13] ----------
__global__ __launch_bounds__(256)
void rel_k(const u16* __restrict__ qg, const float* __restrict__ rph,
           const float* __restrict__ rpw, float* __restrict__ relh,
           float* __restrict__ relw) {
  int wh = blockIdx.x;
  for (int pair = (int)threadIdx.x; pair < 392; pair += 256) {
    int table = pair >= 196;
    int q = table ? pair - 196 : pair;
    int qi = q / 14, qj = q - qi * 14;
    int qq = table ? qj : qi;
    const u16* qr = qg + ((size_t)wh * 196 + q) * 64;
    float qv[64];
#pragma unroll
    for (int c8 = 0; c8 < 8; ++c8) {
      u16x8 u = *(const u16x8*)(qr + c8 * 8);
#pragma unroll
      for (int j = 0; j < 8; ++j) qv[c8 * 8 + j] = bf2f(u[j]);
    }
    const float* rp = table ? rpw : rph;
    float* out = (table ? relw : relh) + ((size_t)wh * 196 + q) * 14;
    for (int kq = 0; kq < 14; ++kq) {
      const float* rrow = rp + (qq - kq + 13) * 64;
      float sum = 0.f;
#pragma unroll
      for (int c4 = 0; c4 < 16; ++c4) {
        float4 rv = *(const float4*)(rrow + c4 * 4);
        sum += qv[c4 * 4] * rv.x + qv[c4 * 4 + 1] * rv.y +
               qv[c4 * 4 + 2] * rv.z + qv[c4 * 4 + 3] * rv.w;
      }
      out[kq] = sum;
    }
  }
}

// ---------- windowed attention: one block per (window,head), 4 waves ----------
// Swapped QK^T (S^T = K@Q^T) so the key-softmax is lane-local + 2 shuffles.
// K (25KB) and V^T (32KB, rows padded to 256 elems) are staged ONCE into LDS
// with the chunk-XOR swizzle (pre-swizzled global source, linear glds dest);
// kt/PV loops read LDS instead of re-issuing ~700MB of global traffic.
// p_lds and o_lds are unioned into one scratch (disjoint lifetimes per wave).
__global__ __launch_bounds__(256)
void attn_k(const u16* __restrict__ qg, const u16* __restrict__ kg,
            const u16* __restrict__ vg, const float* __restrict__ relh,
            const float* __restrict__ relw, u16* __restrict__ outb,
            const u16* __restrict__ zeros) {
  __shared__ u16 K_lds[196 * 64];     // 25088 B, chunk-XOR swizzled rows
  __shared__ u16 V_lds[64 * 256];     // 32768 B, V^T rows padded 224->256
  __shared__ float scr[4][64 * 17];   // 17408 B: p (j*16+r) U o (row*17+q)
  const int wh = blockIdx.x;
  const int tid = (int)threadIdx.x;
  const int w = tid >> 6, l = tid & 63;
  const int g = l >> 4, r = l & 15;
  const int win = wh >> 4, head = wh & 15;
  const size_t kbase = (size_t)wh * 196 * 64;
  const size_t vbase = (size_t)wh * 64 * 224;
  // ---- stage K: 1568 x 16B chunks, source chunk XORed with row&7 ----
#pragma unroll
  for (int rd = 0; rd < 6; ++rd) {
    int idx = rd * 256 + tid;
    int trow = idx >> 3, tch = idx & 7;
    glds16(kg + kbase + trow * 64 + ((tch ^ (trow & 7)) << 3), &K_lds[idx * 8]);
  }
  { int idx = 1536 + tid;
    if (idx < 1568) {
      int trow = idx >> 3, tch = idx & 7;
      glds16(kg + kbase + trow * 64 + ((tch ^ (trow & 7)) << 3), &K_lds[idx * 8]);
    } }
  // ---- stage V^T: 64 rows x 32 chunks; slots whose source chunk >=28 get zeros
#pragma unroll
  for (int rd = 0; rd < 8; ++rd) {
    int idx = rd * 256 + tid;
    int trow = idx >> 5, tch = idx & 31;
    int tchs = tch ^ (trow & 7);
    const u16* src = (tchs < 28) ? (vg + vbase + trow * 224 + (tchs << 3)) : zeros;
    glds16(src, &V_lds[idx * 8]);
  }
  __syncthreads();
  for (int qt = w; qt < 13; qt += 4) {
    int q0 = qt * 16 + r;
    int qc = q0 < 196 ? q0 : 195;
    bf16x8 bq0 = *(const bf16x8*)(qg + kbase + (size_t)qc * 64 + g * 8);
    bf16x8 bq1 = *(const bf16x8*)(qg + kbase + (size_t)qc * 64 + 32 + g * 8);
    f32x4 st[13];
#pragma unroll
    for (int kt = 0; kt < 13; ++kt) {
      int k0 = kt * 16 + r;
      int kc = k0 < 196 ? k0 : 195;
      int sk = kc & 7;
      bf16x8 a0 = *(const bf16x8*)&K_lds[kc * 64 + ((g ^ sk) << 3)];
      bf16x8 a1 = *(const bf16x8*)&K_lds[kc * 64 + (((g + 4) ^ sk) << 3)];
      f32x4 z = {0.f, 0.f, 0.f, 0.f};
      z = mfma_bf16(a0, bq0, z);
      z = mfma_bf16(a1, bq1, z);
      st[kt] = z;
      __builtin_amdgcn_sched_barrier(0);   // bound liveness: no cross-kt hoist
    }
    const float* rh = relh + ((size_t)wh * 196 + qc) * 14;
    const float* rw = relw + ((size_t)wh * 196 + qc) * 14;
    float mx = -3.0e38f;
#pragma unroll
    for (int kt = 0; kt < 13; ++kt)
#pragma unroll
      for (int i = 0; i < 4; ++i) {
        int key = kt * 16 + g * 4 + i;
        float sv;
        if (key < 196) {
          int kh = key / 14; int kw = key - kh * 14;
          sv = st[kt][i] * 0.125f + rh[kh] + rw[kw];
        } else sv = -1e30f;
        st[kt][i] = sv;
        mx = fmaxf(mx, sv);
      }
    mx = fmaxf(mx, __shfl_xor(mx, 16, 64));
    mx = fmaxf(mx, __shfl_xor(mx, 32, 64));
    float sum = 0.f;
#pragma unroll
    for (int kt = 0; kt < 13; ++kt)
#pragma unroll
      for (int i = 0; i < 4; ++i) {
        float e = __expf(st[kt][i] - mx);
        st[kt][i] = e;
        sum += e;
      }
    sum += __shfl_xor(sum, 16, 64);
    sum += __shfl_xor(sum, 32, 64);
    float inv = 1.f / sum;
    f32x4 oacc[4] = {};
#pragma unroll
    for (int c = 0; c < 7; ++c) {
      // stage P^T rows c*32..c*32+31 (wave-local LDS re-layout C/D -> B frag)
#pragma unroll
      for (int f2 = 0; f2 < 2; ++f2) {
        int fi = c * 2 + f2;
#pragma unroll
        for (int i = 0; i < 4; ++i) {
          float pv = (fi < 13) ? st[fi][i] * inv : 0.f;
          scr[w][(f2 * 16 + g * 4 + i) * 16 + r] = pv;
        }
      }
      union { u16 u[8]; bf16x8 b; } pu;
#pragma unroll
      for (int j = 0; j < 8; ++j) pu.u[j] = f2bf(scr[w][(g * 8 + j) * 16 + r]);
      bf16x8 bp = pu.b;
#pragma unroll
      for (int dt = 0; dt < 4; ++dt) {
        int vr = dt * 16 + r;
        int cc = c * 4 + g;
        bf16x8 av = *(const bf16x8*)&V_lds[vr * 256 + ((cc ^ (vr & 7)) << 3)];
        oacc[dt] = mfma_bf16(av, bp, oacc[dt]);   // out^T[d][q]
      }
      __builtin_amdgcn_sched_barrier(0);   // bound liveness: no cross-c hoist
    }
    // transpose out^T -> token-major bf16 via LDS (reuses scr, 17-stride)
#pragma unroll
    for (int dt = 0; dt < 4; ++dt)
#pragma unroll
      for (int i = 0; i < 4; ++i)
        scr[w][(dt * 16 + g * 4 + i) * 17 + r] = oacc[dt][i];
    int ql = l >> 2, dseg = l & 3;
    int q = qt * 16 + ql;
    if (q < 196) {
      int qi2 = q / 14, qj2 = q - qi2 * 14;
      int bb = win >> 2; int wy = (win >> 1) & 1; int wx = win & 1;
      int y = wy * 14 + qi2, xx = wx * 14 + qj2;
      size_t tok = (size_t)bb * 784 + y * 28 + xx;
      u16x8 o0, o1;
#pragma unroll
      for (int jj = 0; jj < 8; ++jj) o0[jj] = f2bf(scr[w][(dseg * 16 + jj) * 17 + ql]);
#pragma unroll
      for (int jj = 0; jj < 8; ++jj) o1[jj] = f2bf(scr[w][(dseg * 16 + 8 + jj) * 17 + ql]);
      *(u16x8*)(outb + tok * 1024 + head * 64 + dseg * 16) = o0;
      *(u16x8*)(outb + tok * 1024 + head * 64 + dseg * 16 + 8) = o1;
    }
  }
}

// ---------- workspace arena (bytes), 226,689,024 total ----------
#define OFF_QKVW  ((size_t)0)            // 6291456
#define OFF_PROJW ((size_t)6291456)      // 2097152
#define OFF_FC1W  ((size_t)8388608)      // 8388608
#define OFF_FC2W  ((size_t)16777216)     // 8388608
#define OFF_C1W   ((size_t)25165824)     // 1048576
#define OFF_C2W   ((size_t)26214400)     // 4718592
#define OFF_C3W   ((size_t)30932992)     // 1048576
#define OFF_ZEROS ((size_t)31981568)     // 4096
// R1 (103,219,200): {qg,kg,vg,relh,relw} -> h3 (102,760,448) -> c3f (51,380,224)
#define OFF_R1    ((size_t)33554432)
#define OFF_QG    (OFF_R1)
#define OFF_KG    ((size_t)59244544)
#define OFF_VG    ((size_t)84934656)     // [1024][64][224] bf16
#define OFF_RELH  ((size_t)114294784)
#define OFF_RELW  ((size_t)125534208)
// R2 (25,690,112): h1
#define OFF_R2    ((size_t)136773632)
// R3 (25,690,112): attnb -> h2 -> x2b (disjoint lifetimes)
#define OFF_R3    ((size_t)162463744)
// R4 (25,690,112): c1f -> c2f
#define OFF_R4    ((size_t)188153856)
// R5 (12,845,056): r1 -> r2
#define OFF_R5    ((size_t)213843968)
#define WS_NEEDED ((size_t)226689024)
// x1f / x2f live in d_out (f32): proj writes it, LN2 reads it,
// fc2 reads-as-resid + rewrites it (same-element RMW), final LN adds into it.

extern "C" void kernel_launch(void* const* d_in, const int* in_sizes, int n_in,
                              void* d_out, int out_size, void* d_ws, size_t ws_size,
                              hipStream_t stream) {
  const float* x    = (const float*)d_in[0];
  const float* ln1w = (const float*)d_in[1];
  const float* ln1b = (const float*)d_in[2];
  const float* qkvw = (const float*)d_in[3];
  const float* qkvb = (const float*)d_in[4];
  const float* projw= (const float*)d_in[5];
  const float* projb= (const float*)d_in[6];
  const float* rph  = (const float*)d_in[7];
  const float* rpw  = (const float*)d_in[8];
  const float* ln2w = (const float*)d_in[9];
  const float* ln2b = (const float*)d_in[10];
  const float* fc1w = (const float*)d_in[11];
  const float* fc1b = (const float*)d_in[12];
  const float* fc2w = (const float*)d_in[13];
  const float* fc2b = (const float*)d_in[14];
  const float* c1w  = (const float*)d_in[15];
  const float* n1w  = (const float*)d_in[16];
  const float* n1b  = (const float*)d_in[17];
  const float* c2w  = (const float*)d_in[18];
  const float* n2w  = (const float*)d_in[19];
  const float* n2b  = (const float*)d_in[20];
  const float* c3w  = (const float*)d_in[21];
  const float* n3w  = (const float*)d_in[22];
  const float* n3b  = (const float*)d_in[23];

  if (ws_size < WS_NEEDED) return;  // clean wrong-answer instead of a fault

  char* ws = (char*)d_ws;
  u16* qkvw_b = (u16*)(ws + OFF_QKVW);
  u16* projw_b= (u16*)(ws + OFF_PROJW);
  u16* fc1w_b = (u16*)(ws + OFF_FC1W);
  u16* fc2w_b = (u16*)(ws + OFF_FC2W);
  u16* c1w_b  = (u16*)(ws + OFF_C1W);
  u16* c2w_b  = (u16*)(ws + OFF_C2W);
  u16* c3w_b  = (u16*)(ws + OFF_C3W);
  u16* zerosp = (u16*)(ws + OFF_ZEROS);
  u16* qg   = (u16*)(ws + OFF_QG);
  u16* kg   = (u16*)(ws + OFF_KG);
  u16* vg   = (u16*)(ws + OFF_VG);
  float* relh = (float*)(ws + OFF_RELH);
  float* relw = (float*)(ws + OFF_RELW);
  u16* h3   = (u16*)(ws + OFF_R1);
  float* c3f = (float*)(ws + OFF_R1);
  u16* h1   = (u16*)(ws + OFF_R2);
  u16* attnb = (u16*)(ws + OFF_R3);
  u16* h2   = (u16*)(ws + OFF_R3);
  u16* x2b  = (u16*)(ws + OFF_R3);
  float* c1f = (float*)(ws + OFF_R4);
  float* c2f = (float*)(ws + OFF_R4);
  u16* r1   = (u16*)(ws + OFF_R5);
  u16* r2   = (u16*)(ws + OFF_R5);
  float* x1f = (float*)d_out;   // x1 and x2 residuals live in d_out

  zero_k<<<1, 256, 0, stream>>>((u32x4*)zerosp);
  // weight conversions (every launch: ws is re-poisoned)
  cast_bf16_k<<<3145728 / 1024, 256, 0, stream>>>(qkvw, qkvw_b, 3145728);
  cast_bf16_k<<<1048576 / 1024, 256, 0, stream>>>(projw, projw_b, 1048576);
  cast_bf16_k<<<4194304 / 1024, 256, 0, stream>>>(fc1w, fc1w_b, 4194304);
  cast_bf16_k<<<4194304 / 1024, 256, 0, stream>>>(fc2w, fc2w_b, 4194304);
  cast_bf16_k<<<524288 / 1024, 256, 0, stream>>>(c1w, c1w_b, 524288);
  cast_bf16_k<<<524288 / 1024, 256, 0, stream>>>(c3w, c3w_b, 524288);
  permute_c2_k<<<2359296 / 256, 256, 0, stream>>>(c2w, c2w_b);

  // LN1 -> h1 bf16
  ln_k<1024, 0><<<TOK / 4, 256, 0, stream>>>(x, ln1w, ln1b, nullptr, h1, nullptr, 1e-5f);
  // QKV gemm -> scatter q/k/v (V pre-transposed)
  gemm_k<0, false><<<dim3(3072 / 128, TOK / 128), 256, 0, stream>>>(
      h1, qkvw_b, TOK, 3072, 1024, qkvb, nullptr, nullptr, nullptr, qg, kg, vg, zerosp);
  // rel-pos tables
  rel_k<<<1024, 256, 0, stream>>>(qg, rph, rpw, relh, relw);
  // attention -> attnb bf16 [TOK][1024]
  attn_k<<<1024, 256, 0, stream>>>(qg, kg, vg, relh, relw, attnb, zerosp);
  // proj + resid(x) -> x1f (in d_out)
  gemm_k<1, false><<<dim3(1024 / 128, TOK / 128), 256, 0, stream>>>(
      attnb, projw_b, TOK, 1024, 1024, projb, x, x1f, nullptr, nullptr, nullptr, nullptr, zerosp);
  // LN2 -> h2
  ln_k<1024, 0><<<TOK / 4, 256, 0, stream>>>(x1f, ln2w, ln2b, nullptr, h2, nullptr, 1e-5f);
  // fc1 + gelu -> h3 bf16
  gemm_k<2, false><<<dim3(4096 / 128, TOK / 128), 256, 0, stream>>>(
      h2, fc1w_b, TOK, 4096, 1024, fc1b, nullptr, nullptr, h3, nullptr, nullptr, nullptr, zerosp);
  // fc2 + resid(x1f,in-place d_out) -> x2f (d_out, f32) + x2b (bf16)
  gemm_k<3, false><<<dim3(1024 / 128, TOK / 128), 256, 0, stream>>>(
      h3, fc2w_b, TOK, 1024, 4096, fc2b, x1f, x1f, x2b, nullptr, nullptr, nullptr, zerosp);
  // conv1 (1x1) -> c1f
  gemm_k<4, false><<<dim3(512 / 128, TOK / 128), 256, 0, stream>>>(
      x2b, c1w_b, TOK, 512, 1024, nullptr, nullptr, c1f, nullptr, nullptr, nullptr, nullptr, zerosp);
  // LN-ch + gelu -> r1 bf16
  ln_k<512, 1><<<TOK / 4, 256, 0, stream>>>(c1f, n1w, n1b, nullptr, r1, nullptr, 1e-6f);
  // conv2 (3x3 implicit gemm, K=4608) -> c2f
  gemm_k<4, true><<<dim3(512 / 128, TOK / 128), 256, 0, stream>>>(
      r1, c2w_b, TOK, 512, 4608, nullptr, nullptr, c2f, nullptr, nullptr, nullptr, nullptr, zerosp);
  // LN-ch + gelu -> r2 bf16
  ln_k<512, 1><<<TOK / 4, 256, 0, stream>>>(c2f, n2w, n2b, nullptr, r2, nullptr, 1e-6f);
  // conv3 (1x1) -> c3f
  gemm_k<4, false><<<dim3(1024 / 128, TOK / 128), 256, 0, stream>>>(
      r2, c3w_b, TOK, 1024, 512, nullptr, nullptr, c3f, nullptr, nullptr, nullptr, nullptr, zerosp);
  // final: d_out = x2f(d_out) + LN-ch(c3f; n3w,n3b)
  ln_k<1024, 2><<<TOK / 4, 256, 0, stream>>>(c3f, n3w, n3b, x1f, nullptr, (float*)d_out, 1e-6f);
}